// Round 1
// baseline (55.737 us; speedup 1.0000x reference)
//
#include <hip/hip_runtime.h>

// QLayer closed form:
// State after RX layer is a product state with independent bits,
// E[1-2*b_w] = cos(x[b,w] + theta[w]).
// CNOT ring => measured bit B_w = XOR of prefix b_0..b_w (w>=1),
// B_0 = XOR of b_1..b_15. XOR of independent +-1 signs multiplies:
//   out[b][0] = prod_{j=1}^{15} cos(ang_j)
//   out[b][w] = prod_{j=0}^{w}  cos(ang_j)   (w = 1..15)
// where ang_j = x[b][j] + theta[j].

#define BATCH 512
#define NW 16

__global__ __launch_bounds__(256) void qlayer_closed_form(
    const float* __restrict__ x, const float* __restrict__ theta,
    float* __restrict__ out)
{
    int b = blockIdx.x * blockDim.x + threadIdx.x;
    if (b >= BATCH) return;

    // Vector-load the 16-float x row (64B-aligned since b*16 floats = 64B).
    float4 xs[4];
    const float4* xv = reinterpret_cast<const float4*>(x + b * NW);
#pragma unroll
    for (int q = 0; q < 4; ++q) xs[q] = xv[q];
    const float* xf = reinterpret_cast<const float*>(xs);

    // theta[j] is wave-uniform -> scalar loads, L1-resident.
    float c[NW];
#pragma unroll
    for (int j = 0; j < NW; ++j)
        c[j] = cosf(xf[j] + theta[j]);

    float o[NW];

    // wire 0: product of c[1..15]
    float s = 1.0f;
#pragma unroll
    for (int j = 1; j < NW; ++j) s *= c[j];
    o[0] = s;

    // wires 1..15: prefix products including c[0]
    float p = c[0];
#pragma unroll
    for (int w = 1; w < NW; ++w) { p *= c[w]; o[w] = p; }

    // Vector-store 16 floats.
    float4* ov = reinterpret_cast<float4*>(out + b * NW);
    const float4* of = reinterpret_cast<const float4*>(o);
#pragma unroll
    for (int q = 0; q < 4; ++q) ov[q] = of[q];
}

extern "C" void kernel_launch(void* const* d_in, const int* in_sizes, int n_in,
                              void* d_out, int out_size, void* d_ws, size_t ws_size,
                              hipStream_t stream)
{
    const float* x     = (const float*)d_in[0];   // [512,16] f32
    const float* theta = (const float*)d_in[1];   // [16]     f32
    float* out = (float*)d_out;                   // [512,16] f32

    qlayer_closed_form<<<dim3((BATCH + 255) / 256), dim3(256), 0, stream>>>(x, theta, out);
}